// Round 2
// baseline (248.897 us; speedup 1.0000x reference)
//
#include <hip/hip_runtime.h>
#include <stdint.h>

// DilatedMask fused: mask = (x == 0), 33x33 sliding max (SAME) == binary dilation.
// Single kernel: each block packs its 64-row strip (32 out rows + 2*16 halo)
// from the float raster directly into LDS via ballot (1 bit/px), vertical OR,
// horizontal OR of +-16 bit shifts with neighbor-word carries, unpack to
// int32 0/1, non-temporal int4 stores. No workspace, no packed round-trip,
// read and write streams overlap. Halo rows are re-read 2x; XCD-aware tile
// swizzle keeps neighboring tiles on the same XCD L2 so re-reads hit cache.

#define HH 2048
#define WPX 2048
#define WW 32            // uint64 words per row (2048 bits)
#define RAD 16
#define ROWS 32          // output rows per block
#define SROWS (ROWS + 2 * RAD)   // 64 staged rows
#define TPB 512

typedef float vfloat4 __attribute__((ext_vector_type(4)));
typedef int   vint4   __attribute__((ext_vector_type(4)));

// spread bit k -> bit 4k (16 bits -> 64 bits)
__device__ __forceinline__ uint64_t spread4(uint64_t x) {
  x &= 0xFFFFULL;
  x = (x | (x << 24)) & 0x000000FF000000FFULL;
  x = (x | (x << 12)) & 0x000F000F000F000FULL;
  x = (x | (x << 6))  & 0x0303030303030303ULL;
  x = (x | (x << 3))  & 0x1111111111111111ULL;
  return x;
}

__global__ __launch_bounds__(TPB) void fused_dilate_kernel(const float* __restrict__ x,
                                                           int* __restrict__ out) {
  __shared__ uint64_t stage[SROWS][WW];    // 64*32*8 = 16 KiB
  __shared__ uint64_t vall[ROWS][WW + 2];  // zero guard columns, 8.5 KiB
  __shared__ uint64_t hrow[ROWS][WW];      // 8 KiB

  // XCD-aware swizzle: 512 blocks, 8 XCDs, 64 consecutive tiles per XCD so
  // halo-sharing neighbor tiles are co-resident on one XCD's L2.
  const int cpx = gridDim.x >> 3;                       // 64
  const int tile = (blockIdx.x & 7) * cpx + (blockIdx.x >> 3);
  const int gr0 = tile * ROWS;                          // 2048 % 32 == 0: never straddles images
  const int n  = gr0 >> 11;
  const int h0 = gr0 & (HH - 1);
  const float* xb = x + (long long)n * HH * WPX;

  const int t = threadIdx.x;
  const int lane = t & 63;
  const int wv = t >> 6;                                // wave 0..7: px [wv*256, wv*256+256)

  // --- pack phase: 64 rows x 2048 px, one full row per loop iteration ---
  // Cached (non-nt) loads: halo rows are read by 2 blocks -> want L2/L3 hits.
#pragma unroll 8
  for (int rr = 0; rr < SROWS; ++rr) {
    int hh = h0 + rr - RAD;
    hh = hh < 0 ? 0 : (hh > HH - 1 ? HH - 1 : hh);      // clamp == clipped SAME (OR-idempotent)
    const vfloat4 v = *(const vfloat4*)(xb + (long long)hh * WPX + (t << 2));
    const unsigned long long m0 = __ballot(v.x == 0.0f);
    const unsigned long long m1 = __ballot(v.y == 0.0f);
    const unsigned long long m2 = __ballot(v.z == 0.0f);
    const unsigned long long m3 = __ballot(v.w == 0.0f);
    if ((lane & 15) == 0) {
      const int sh = lane;                              // j*16, j = lane>>4
      stage[rr][(wv << 2) + (lane >> 4)] =
          spread4(m0 >> sh) | (spread4(m1 >> sh) << 1) |
          (spread4(m2 >> sh) << 2) | (spread4(m3 >> sh) << 3);
    }
  }
  __syncthreads();

  const int w = t & 31;
  const int r = t >> 5;                                 // 0..15, each thread does 2 rows

  // --- vertical OR: 33-row window from stage ---
#pragma unroll
  for (int rb = 0; rb < ROWS / 16; ++rb) {
    const int rr = r + rb * 16;
    uint64_t v = 0;
#pragma unroll
    for (int i = 0; i <= 2 * RAD; ++i) v |= stage[rr + i][w];
    vall[rr][w + 1] = v;
    if (w == 0) { vall[rr][0] = 0; vall[rr][WW + 1] = 0; }
  }
  __syncthreads();

  // --- horizontal OR: +-16 bit shifts with neighbor-word carries ---
#pragma unroll
  for (int rb = 0; rb < ROWS / 16; ++rb) {
    const int rr = r + rb * 16;
    const uint64_t p  = vall[rr][w];
    const uint64_t c  = vall[rr][w + 1];
    const uint64_t nx = vall[rr][w + 2];
    uint64_t res = c;
#pragma unroll
    for (int s = 1; s <= RAD; ++s) {
      res |= (c >> s) | (nx << (64 - s));
      res |= (c << s) | (p >> (64 - s));
    }
    hrow[rr][w] = res;
  }
  __syncthreads();

  // --- unpack + store: 32 rows x 2048 px = 16384 int4, 32/thread, coalesced, nt ---
  int* obase = out + (long long)gr0 * WPX;
#pragma unroll
  for (int it = 0; it < ROWS * (WPX / 4) / TPB; ++it) { // 32 iters
    const int f = it * TPB + t;                         // int4 index in tile
    const int row_l = f >> 9;                           // 512 int4 per row
    const int wi = (f >> 4) & 31;                       // 16 int4 per word
    const int sh = (f & 15) * 4;
    const uint64_t bits = hrow[row_l][wi] >> sh;        // same-word broadcast: conflict-free
    vint4 o;
    o.x = (int)(bits & 1);
    o.y = (int)((bits >> 1) & 1);
    o.z = (int)((bits >> 2) & 1);
    o.w = (int)((bits >> 3) & 1);
    __builtin_nontemporal_store(o, (vint4*)(obase + (long long)f * 4));
  }
}

extern "C" void kernel_launch(void* const* d_in, const int* in_sizes, int n_in,
                              void* d_out, int out_size, void* d_ws, size_t ws_size,
                              hipStream_t stream) {
  const float* x = (const float*)d_in[0];
  int* out = (int*)d_out;
  // 8 images * (2048/32) tiles = 512 blocks, 2 per CU (LDS 32.5 KiB, 8 waves)
  hipLaunchKernelGGL(fused_dilate_kernel, dim3(512), dim3(TPB), 0, stream, x, out);
}